// Round 16
// baseline (125.876 us; speedup 1.0000x reference)
//
#include <hip/hip_runtime.h>
#include <math.h>

// Problem constants
#define BB 4
#define TT 4096
#define CC 1024
#define HS 64
#define KSEL 2048
#define NSPL 16   // KV splits per row-block
#define SWLOG 8   // split width = 256
#define SW 256

typedef float f32x4 __attribute__((ext_vector_type(4)));
typedef short short8 __attribute__((ext_vector_type(8)));

__device__ __forceinline__ unsigned short f2bf(float f) {
  union { float f; unsigned int u; } c;
  c.f = f;
  const unsigned int u = c.u;
  return (unsigned short)((u + 0x7FFFu + ((u >> 16) & 1u)) >> 16);  // RTNE
}

// packed f32x2 -> bf16x2 (RTNE), single HW instruction
__device__ __forceinline__ unsigned cvtpk(float lo, float hi) {
  unsigned r;
  asm("v_cvt_pk_bf16_f32 %0, %1, %2" : "=v"(r) : "v"(lo), "v"(hi));
  return r;
}

// ---------------------------------------------------------------------------
// conv_w: Wq|Wk|Wv fp32 -> bf16 B-fragment layout; also zeroes xsum.
// ---------------------------------------------------------------------------
__global__ __launch_bounds__(256) void conv_w(const float* __restrict__ Wq,
                                              const float* __restrict__ Wk,
                                              const float* __restrict__ Wv,
                                              unsigned short* __restrict__ wbf,
                                              float* __restrict__ xsum) {
  const int gid = blockIdx.x * 256 + threadIdx.x;  // 0..24575
  if (gid < 1024) ((float4*)xsum)[gid] = make_float4(0.f, 0.f, 0.f, 0.f);
  const int kt = gid / 768;
  const int rem = gid - kt * 768;
  const int nt = rem >> 6, lane = rem & 63;
  const int col = nt * 16 + (lane & 15);
  const float* W = (col < 64) ? Wq : ((col < 128) ? Wk : Wv);
  const int cl = col & 63;
  const int k0 = kt * 32 + (lane >> 4) * 8;
  unsigned short tmp[8];
#pragma unroll
  for (int i = 0; i < 8; i++) tmp[i] = f2bf(W[(size_t)(k0 + i) * HS + cl]);
  uint4 o;
  o.x = tmp[0] | ((unsigned)tmp[1] << 16);
  o.y = tmp[2] | ((unsigned)tmp[3] << 16);
  o.z = tmp[4] | ((unsigned)tmp[5] << 16);
  o.w = tmp[6] | ((unsigned)tmp[7] << 16);
  *(uint4*)(wbf + (size_t)gid * 8) = o;
}

// ---------------------------------------------------------------------------
// fusedproj (R6/R13-proven): reads x ONCE. 512 blocks x 32 rows. Per 256-col
// chunk: stage bf16 into XOR-swizzled LDS, atomicAdd fp32 column sums into
// xsum, MFMA against wbf (L2-hot). Writes q (prescaled 2^-5), k row-major
// bf16, V transposed vt[b][d][t].
// ---------------------------------------------------------------------------
#define PR 32
__global__ __launch_bounds__(256) void fusedproj(
    const float* __restrict__ x, const unsigned short* __restrict__ wbf,
    float* __restrict__ xsum, unsigned short* __restrict__ qbf,
    unsigned short* __restrict__ kbf, unsigned short* __restrict__ vtbf) {
  __shared__ unsigned short Xs[PR][256];  // 16 KB, granule-XOR-swizzled
  __shared__ float xsred[4][256];
  const int rb = blockIdx.x;  // 512 blocks
  const size_t r0 = (size_t)rb * PR;
  const int tid = threadIdx.x;
  const int wid = tid >> 6, lane = tid & 63;
  const int lhi = lane >> 4, llo = lane & 15;
  const int mt = wid >> 1, nh = wid & 1;
  const int cl = tid & 63, rg = tid >> 6;
  const int bidx = rb >> 7;

  f32x4 acc[6];
#pragma unroll
  for (int n = 0; n < 6; n++) acc[n] = (f32x4){0.f, 0.f, 0.f, 0.f};

  float4 pf[8];
#pragma unroll
  for (int rr = 0; rr < 8; rr++)
    pf[rr] = *(const float4*)(x + (r0 + rg * 8 + rr) * CC + cl * 4);

  for (int ch = 0; ch < 4; ch++) {
    float ps0 = 0.f, ps1 = 0.f, ps2 = 0.f, ps3 = 0.f;
#pragma unroll
    for (int rr = 0; rr < 8; rr++) {
      const int row = rg * 8 + rr;
      float4 v = pf[rr];
      ps0 += v.x; ps1 += v.y; ps2 += v.z; ps3 += v.w;
      *(uint2*)((char*)&Xs[0][0] + row * 512 +
                ((((cl >> 1) ^ (row & 7))) << 4) + ((cl & 1) << 3)) =
          make_uint2(cvtpk(v.x, v.y), cvtpk(v.z, v.w));
    }
    xsred[rg][cl * 4 + 0] = ps0;
    xsred[rg][cl * 4 + 1] = ps1;
    xsred[rg][cl * 4 + 2] = ps2;
    xsred[rg][cl * 4 + 3] = ps3;
    __syncthreads();
    // issue next-chunk prefetch NOW; latency hides under atomic + MFMA
    if (ch < 3) {
#pragma unroll
      for (int rr = 0; rr < 8; rr++)
        pf[rr] = *(const float4*)(x + (r0 + rg * 8 + rr) * CC +
                                  (ch + 1) * 256 + cl * 4);
    }
    atomicAdd(&xsum[bidx * CC + ch * 256 + tid],
              xsred[0][tid] + xsred[1][tid] + xsred[2][tid] + xsred[3][tid]);
    const int row = mt * 16 + llo;
#pragma unroll
    for (int ktl = 0; ktl < 8; ktl++) {
      short8 af = *(const short8*)((const char*)&Xs[0][0] + row * 512 +
                                   ((((ktl << 2) + lhi) ^ (row & 7)) << 4));
      const unsigned short* bp =
          wbf + (((size_t)(ch * 8 + ktl) * 12 + nh * 6) * 64 + lane) * 8;
#pragma unroll
      for (int n = 0; n < 6; n++) {
        short8 bf = *(const short8*)(bp + n * 64 * 8);
        acc[n] = __builtin_amdgcn_mfma_f32_16x16x32_bf16(af, bf, acc[n], 0, 0, 0);
      }
    }
    __syncthreads();
  }
  const int rbg = (int)r0 + mt * 16 + lhi * 4;
#pragma unroll
  for (int n = 0; n < 6; n++) {
    const int col = (nh * 6 + n) * 16 + llo;
    const int mat = col >> 6, cl2 = col & 63;
    if (mat == 0) {
#pragma unroll
      for (int r = 0; r < 4; r++)
        qbf[(size_t)(rbg + r) * HS + cl2] = f2bf(acc[n][r] * 0.03125f);
    } else if (mat == 1) {
#pragma unroll
      for (int r = 0; r < 4; r++)
        kbf[(size_t)(rbg + r) * HS + cl2] = f2bf(acc[n][r]);
    } else {
      const int bb = rbg >> 12, tloc = rbg & (TT - 1);
      *(uint2*)(vtbf + ((size_t)bb * HS + cl2) * TT + tloc) =
          make_uint2(cvtpk(acc[n][0], acc[n][1]), cvtpk(acc[n][2], acc[n][3]));
    }
  }
}

// ---------------------------------------------------------------------------
// rowsums_x (R15-proven conflict-free): 256 blocks x 512 thr. Lane qu reads
// elements (qu + e*8)*4 -- all 32 banks hit exactly once per wave access.
// Prologue computes w = Wq (Wk^T xsum); main: rs[row] = x[row] . w.
// ---------------------------------------------------------------------------
__global__ __launch_bounds__(512) void rowsums_x(
    const float* __restrict__ x, const float* __restrict__ Wq,
    const float* __restrict__ Wk, const float* __restrict__ xsum,
    float* __restrict__ rs) {
  __shared__ float xsl[CC];
  __shared__ float kred[8][HS];
  __shared__ float ksl[HS];
  __shared__ float wl[CC];
  const int g = blockIdx.x;  // 256 blocks
  const int tid = threadIdx.x;
  const int b = g >> 6;
  *(float2*)(xsl + tid * 2) = *(const float2*)(xsum + b * CC + tid * 2);
  __syncthreads();
  {
    const int g8 = tid >> 6, d = tid & 63;
    const float* wkp = Wk + (size_t)(g8 * 128) * HS + d;
    float s = 0.f;
    for (int c = 0; c < 128; c++) s += xsl[g8 * 128 + c] * wkp[(size_t)c * HS];
    kred[g8][d] = s;
  }
  __syncthreads();
  if (tid < 64) {
    float s = 0.f;
#pragma unroll
    for (int g8 = 0; g8 < 8; g8++) s += kred[g8][tid];
    ksl[tid] = s;
  }
  __syncthreads();
#pragma unroll
  for (int p = 0; p < 2; p++) {
    const int c = tid * 2 + p;
    const float* wqp = Wq + (size_t)c * HS;
    float s = 0.f;
#pragma unroll
    for (int d4 = 0; d4 < 16; d4++) {
      float4 a = *(const float4*)(wqp + d4 * 4);
      float4 kk = *(const float4*)(ksl + d4 * 4);
      s += a.x * kk.x + a.y * kk.y + a.z * kk.z + a.w * kk.w;
    }
    wl[c] = s;
  }
  __syncthreads();
  const size_t row = (size_t)g * 64 + (tid >> 3);
  const int qu = tid & 7;
  const float* xr = x + row * CC;
  float s = 0.f;
#pragma unroll
  for (int e = 0; e < 32; e++) {
    const int off = (qu + e * 8) * 4;
    float4 v = *(const float4*)(xr + off);
    float4 w4 = *(const float4*)(wl + off);
    s += v.x * w4.x + v.y * w4.y + v.z * w4.z + v.w * w4.w;
  }
  s += __shfl_xor(s, 1);
  s += __shfl_xor(s, 2);
  s += __shfl_xor(s, 4);
  if (qu == 0) rs[row] = s;
}

// ---------------------------------------------------------------------------
// rankk (R6-proven): flag[t] = t in top-2048 (ties: lower index). 512 blocks.
// ---------------------------------------------------------------------------
__global__ __launch_bounds__(256) void rankk(const float* __restrict__ rs,
                                             int* __restrict__ flag) {
  __shared__ float rl[TT];
  const int g = blockIdx.x;  // B*128
  const int b = g >> 7, chunk = g & 127;
  const int tid = threadIdx.x;
  const float* rsb = rs + (size_t)b * TT;
  for (int e = tid; e < TT / 4; e += 256)
    *(float4*)(rl + e * 4) = *(const float4*)(rsb + e * 4);
  __syncthreads();
  const int cand = tid >> 3, qu = tid & 7;
  const int t = chunk * 32 + cand;
  const float my = rl[t];
  int cnt = 0;
  for (int e = 0; e < 128; e++) {
    const int s = qu * 512 + e * 4;
    float4 v = *(const float4*)(rl + s);
    cnt += (v.x > my) || (v.x == my && (s + 0) < t);
    cnt += (v.y > my) || (v.y == my && (s + 1) < t);
    cnt += (v.z > my) || (v.z == my && (s + 2) < t);
    cnt += (v.w > my) || (v.w == my && (s + 3) < t);
  }
  cnt += __shfl_xor(cnt, 1);
  cnt += __shfl_xor(cnt, 2);
  cnt += __shfl_xor(cnt, 4);
  if (qu == 0) flag[(size_t)b * TT + t] = (cnt < KSEL) ? 1 : 0;
}

// ---------------------------------------------------------------------------
// In-block compaction helper: 256 threads scan one batch's 4096 flags into
// LDS idx (ascending). Deterministic; every block derives identical results
// from identical flags (kernel-boundary visibility -- NO device fences).
// ---------------------------------------------------------------------------
__device__ __forceinline__ void compact_to_lds(const int* __restrict__ fb,
                                               int* __restrict__ idx_l,
                                               int* __restrict__ wsum,
                                               int* __restrict__ woff,
                                               int tid, int wid, int lane) {
  const int base = tid * 16;
  int f[16];
  int cnt = 0;
#pragma unroll
  for (int e4 = 0; e4 < 4; e4++) {
    int4 v = *(const int4*)(fb + base + e4 * 4);
    f[e4 * 4 + 0] = v.x; f[e4 * 4 + 1] = v.y;
    f[e4 * 4 + 2] = v.z; f[e4 * 4 + 3] = v.w;
    cnt += v.x + v.y + v.z + v.w;
  }
  int sc = cnt;
#pragma unroll
  for (int d = 1; d < 64; d <<= 1) {
    int v = __shfl_up(sc, d);
    if (lane >= d) sc += v;
  }
  if (lane == 63) wsum[wid] = sc;
  __syncthreads();
  if (tid == 0) {
    int a = 0;
#pragma unroll
    for (int w = 0; w < 4; w++) { woff[w] = a; a += wsum[w]; }
  }
  __syncthreads();
  int pos = woff[wid] + sc - cnt;
#pragma unroll
  for (int e = 0; e < 16; e++)
    if (f[e]) idx_l[pos++] = base + e;
}

// ---------------------------------------------------------------------------
// attn_mfma: compact-free. Prologue: in-block compaction of ALL 4 batches
// into LDS + per-(b,rb) exclusive-scan table; unit decode via binary search.
// Main: worklist-dense grid-stride; inner compute identical to R6/R15
// (swapped QK^T + no-max softmax, ping-pong K/V prefetch, streaming pl/pacc).
// ---------------------------------------------------------------------------
struct KF { short8 a0, a1, b0, b1; };
struct VF { short8 v0, v1, v2, v3; };

__global__ __launch_bounds__(256) void attn_mfma(
    const unsigned short* __restrict__ qbf,
    const unsigned short* __restrict__ kbf,
    const unsigned short* __restrict__ vtbf, const int* __restrict__ flag,
    float* __restrict__ pl, float* __restrict__ pacc) {
  __shared__ unsigned short P_lds[4][32][40];  // 10.2 KB
  __shared__ int idx_l[BB][KSEL];              // 32 KB
  __shared__ int excl[257];                    // ~1 KB
  __shared__ int wsum[4];
  __shared__ int woff[4];
  const int tid = threadIdx.x;
  const int wid = tid >> 6, lane = tid & 63;
  const int lhi = lane >> 4, llo = lane & 15;

  // ---- prologue: redundant compaction (replaces the compact dispatch) ----
#pragma unroll 1
  for (int b = 0; b < BB; b++) {
    compact_to_lds(flag + (size_t)b * TT, idx_l[b], wsum, woff, tid, wid, lane);
    __syncthreads();
  }
  {
    // per-(b,rb) active-split count -> exclusive scan (g = tid: b=g>>6,rb=g&63)
    const int na = (idx_l[tid >> 6][(tid & 63) * 32 + 31] >> SWLOG) + 1;
    int sc = na;
#pragma unroll
    for (int d = 1; d < 64; d <<= 1) {
      int v = __shfl_up(sc, d);
      if (lane >= d) sc += v;
    }
    if (lane == 63) wsum[wid] = sc;
    __syncthreads();
    if (tid == 0) {
      int a = 0;
#pragma unroll
      for (int w = 0; w < 4; w++) { woff[w] = a; a += wsum[w]; }
      excl[256] = a;
    }
    __syncthreads();
    excl[tid] = woff[wid] + sc - na;
    __syncthreads();
  }
  const int total = excl[256];

  for (int u = blockIdx.x * 4 + wid; u < total; u += gridDim.x * 4) {
    // decode unit -> (g, s) via binary search over excl (ascending)
    int g = 0;
#pragma unroll
    for (int step = 128; step; step >>= 1)
      if (g + step < 256 && excl[g + step] <= u) g += step;
    const int b = g >> 6, rb = g & 63;
    const int s = u - excl[g];
    const int* idxb = idx_l[b];
    const int rloc = rb * 32;
    const size_t rbase = (size_t)b * KSEL + rloc;
    const int tmaxblk = idxb[rloc + 31];
    const int jlo = s << SWLOG;

    const int trow0 = idxb[rloc + llo];
    const int trow1 = idxb[rloc + 16 + llo];
    short8 qf[2][2];
    {
      const unsigned short* qp0 = qbf + ((size_t)b * TT + trow0) * HS + lhi * 8;
      const unsigned short* qp1 = qbf + ((size_t)b * TT + trow1) * HS + lhi * 8;
      qf[0][0] = *(const short8*)(qp0);
      qf[0][1] = *(const short8*)(qp0 + 32);
      qf[1][0] = *(const short8*)(qp1);
      qf[1][1] = *(const short8*)(qp1 + 32);
    }
    f32x4 o[2][4];
#pragma unroll
    for (int mtt = 0; mtt < 2; mtt++)
#pragma unroll
      for (int n = 0; n < 4; n++) o[mtt][n] = (f32x4){0.f, 0.f, 0.f, 0.f};
    float lsum[2] = {0.f, 0.f};

    const unsigned short* kb = kbf + (size_t)b * TT * HS;
    const unsigned short* vb = vtbf + (size_t)b * HS * TT;
    const int jend = min(tmaxblk + 1, jlo + SW);

    auto loadK = [&](int j0) {
      KF K;
      const unsigned short* kp = kb + (size_t)(j0 + llo) * HS + lhi * 8;
      K.a0 = *(const short8*)(kp);
      K.a1 = *(const short8*)(kp + 32);
      K.b0 = *(const short8*)(kp + 16 * HS);
      K.b1 = *(const short8*)(kp + 16 * HS + 32);
      return K;
    };
    auto loadV = [&](int j0) {
      VF V;
      const unsigned short* vp = vb + (size_t)llo * TT + j0 + lhi * 8;
      V.v0 = *(const short8*)(vp);
      V.v1 = *(const short8*)(vp + 16 * TT);
      V.v2 = *(const short8*)(vp + 32 * TT);
      V.v3 = *(const short8*)(vp + 48 * TT);
      return V;
    };

    auto body = [&](int j0, const KF& K, const VF& V) {
      f32x4 sc2[2][2];
#pragma unroll
      for (int mtt = 0; mtt < 2; mtt++) {
        f32x4 a = (f32x4){0.f, 0.f, 0.f, 0.f};
        a = __builtin_amdgcn_mfma_f32_16x16x32_bf16(K.a0, qf[mtt][0], a, 0, 0, 0);
        a = __builtin_amdgcn_mfma_f32_16x16x32_bf16(K.a1, qf[mtt][1], a, 0, 0, 0);
        sc2[mtt][0] = a;
        f32x4 c = (f32x4){0.f, 0.f, 0.f, 0.f};
        c = __builtin_amdgcn_mfma_f32_16x16x32_bf16(K.b0, qf[mtt][0], c, 0, 0, 0);
        c = __builtin_amdgcn_mfma_f32_16x16x32_bf16(K.b1, qf[mtt][1], c, 0, 0, 0);
        sc2[mtt][1] = c;
      }
#pragma unroll
      for (int mtt = 0; mtt < 2; mtt++) {
        const int tr = (mtt == 0) ? trow0 : trow1;
        float p[8];
#pragma unroll
        for (int kt = 0; kt < 2; kt++)
#pragma unroll
          for (int r = 0; r < 4; r++) {
            const int kk = j0 + kt * 16 + lhi * 4 + r;
            const float ex = __expf(sc2[mtt][kt][r]);
            p[kt * 4 + r] = (kk <= tr) ? ex : 0.f;
          }
        lsum[mtt] += ((p[0] + p[1]) + (p[2] + p[3])) +
                     ((p[4] + p[5]) + (p[6] + p[7]));
        *(uint2*)&P_lds[wid][mtt * 16 + llo][lhi * 4] =
            make_uint2(cvtpk(p[0], p[1]), cvtpk(p[2], p[3]));
        *(uint2*)&P_lds[wid][mtt * 16 + llo][16 + lhi * 4] =
            make_uint2(cvtpk(p[4], p[5]), cvtpk(p[6], p[7]));
      }
      // PV (same-wave DS ordering -> no barrier needed)
      short8 pa0 = *(const short8*)&P_lds[wid][llo][lhi * 8];
      short8 pa1 = *(const short8*)&P_lds[wid][16 + llo][lhi * 8];
      o[0][0] = __builtin_amdgcn_mfma_f32_16x16x32_bf16(pa0, V.v0, o[0][0], 0, 0, 0);
      o[1][0] = __builtin_amdgcn_mfma_f32_16x16x32_bf16(pa1, V.v0, o[1][0], 0, 0, 0);
      o[0][1] = __builtin_amdgcn_mfma_f32_16x16x32_bf16(pa0, V.v1, o[0][1], 0, 0, 0);
      o[1][1] = __builtin_amdgcn_mfma_f32_16x16x32_bf16(pa1, V.v1, o[1][1], 0, 0, 0);
      o[0][2] = __builtin_amdgcn_mfma_f32_16x16x32_bf16(pa0, V.v2, o[0][2], 0, 0, 0);
      o[1][2] = __builtin_amdgcn_mfma_f32_16x16x32_bf16(pa1, V.v2, o[1][2], 0, 0, 0);
      o[0][3] = __builtin_amdgcn_mfma_f32_16x16x32_bf16(pa0, V.v3, o[0][3], 0, 0, 0);
      o[1][3] = __builtin_amdgcn_mfma_f32_16x16x32_bf16(pa1, V.v3, o[1][3], 0, 0, 0);
    };

    int j0 = jlo;
    KF ka = loadK(j0), kb2;
    VF va = loadV(j0), vb2;
    for (;;) {
      if (j0 + 32 < jend) { kb2 = loadK(j0 + 32); vb2 = loadV(j0 + 32); }
      body(j0, ka, va);
      j0 += 32;
      if (j0 >= jend) break;
      if (j0 + 32 < jend) { ka = loadK(j0 + 32); va = loadV(j0 + 32); }
      body(j0, kb2, vb2);
      j0 += 32;
      if (j0 >= jend) break;
    }

    // epilogue: streaming partial writes (combine is a plain sum)
    lsum[0] += __shfl_xor(lsum[0], 16);
    lsum[0] += __shfl_xor(lsum[0], 32);
    lsum[1] += __shfl_xor(lsum[1], 16);
    lsum[1] += __shfl_xor(lsum[1], 32);
    if (lane < 16) {
      pl[(rbase + llo) * NSPL + s] = lsum[0];
      pl[(rbase + 16 + llo) * NSPL + s] = lsum[1];
    }
#pragma unroll
    for (int mtt = 0; mtt < 2; mtt++)
#pragma unroll
      for (int r = 0; r < 4; r++) {
        const size_t rowi = rbase + mtt * 16 + lhi * 4 + r;
#pragma unroll
        for (int n = 0; n < 4; n++)
          pacc[(rowi * NSPL + s) * HS + n * 16 + llo] = o[mtt][n][r];
      }
  }
}

// ---------------------------------------------------------------------------
// attn_combine: compact-free. Prologue re-derives its batch's idx from flags
// in LDS; then plain sums over active splits + normalize.
// ---------------------------------------------------------------------------
__global__ __launch_bounds__(256) void attn_combine(
    const float* __restrict__ pl, const float* __restrict__ pacc,
    const int* __restrict__ flag, float* __restrict__ out) {
  __shared__ int idx_l[KSEL];  // 8 KB
  __shared__ int wsum[4];
  __shared__ int woff[4];
  const int b = blockIdx.x;
  const int i0 = blockIdx.y * 32;
  const int tid = threadIdx.x;
  const int wid = tid >> 6, lane = tid & 63;
  compact_to_lds(flag + (size_t)b * TT, idx_l, wsum, woff, tid, wid, lane);
  __syncthreads();

  const int r = tid >> 3, dg = tid & 7;
  const size_t rowi = (size_t)b * KSEL + i0 + r;
  const int t_r = idx_l[i0 + r];
  const int ns = (t_r >> SWLOG) + 1;
  float L = 0.f;
  float o[8] = {0.f, 0.f, 0.f, 0.f, 0.f, 0.f, 0.f, 0.f};
  for (int s = 0; s < ns; s++) {
    L += pl[rowi * NSPL + s];
    const float* pa = pacc + (rowi * NSPL + s) * HS + dg * 8;
    float4 a0 = *(const float4*)(pa);
    float4 a1 = *(const float4*)(pa + 4);
    o[0] += a0.x; o[1] += a0.y; o[2] += a0.z; o[3] += a0.w;
    o[4] += a1.x; o[5] += a1.y; o[6] += a1.z; o[7] += a1.w;
  }
  const float invl = 1.0f / L;
  float* op = out + rowi * HS + dg * 8;
  *(float4*)(op) = make_float4(o[0] * invl, o[1] * invl, o[2] * invl, o[3] * invl);
  *(float4*)(op + 4) = make_float4(o[4] * invl, o[5] * invl, o[6] * invl, o[7] * invl);
}

// ---------------------------------------------------------------------------
extern "C" void kernel_launch(void* const* d_in, const int* in_sizes, int n_in,
                              void* d_out, int out_size, void* d_ws,
                              size_t ws_size, hipStream_t stream) {
  const float* x = (const float*)d_in[0];
  const float* Wq = (const float*)d_in[1];
  const float* Wk = (const float*)d_in[2];
  const float* Wv = (const float*)d_in[3];
  float* out = (float*)d_out;

  float* wsf = (float*)d_ws;
  // Region 0..33.55MB: pacc (attn phase) overlaps selection-phase scratch
  // (xsum, rs, wbf), all dead before attn_mfma runs. flag must SURVIVE into
  // attn/combine, so it lives past pacc.
  float* pacc = wsf;                         // 8,388,608 f (BB*KSEL*NSPL*HS)
  float* xsum = wsf;                         // 4,096 f (atomic accum)
  float* rs = xsum + 4096;                   // 16,384 f
  unsigned short* wbf = (unsigned short*)(rs + 16384);  // 196,608 us
  // Past pacc: buffers live through attn.
  unsigned short* qbf = (unsigned short*)(pacc + 8388608);  // 1,048,576 us
  unsigned short* kbf = qbf + 1048576;       // 1,048,576 us
  unsigned short* vtbf = kbf + 1048576;      // 1,048,576 us
  int* flag = (int*)(vtbf + 1048576);        // 16,384 i
  float* pl = (float*)(flag + 16384);        // 131,072 f

  conv_w<<<96, 256, 0, stream>>>(Wq, Wk, Wv, wbf, xsum);
  fusedproj<<<512, 256, 0, stream>>>(x, wbf, xsum, qbf, kbf, vtbf);
  rowsums_x<<<256, 512, 0, stream>>>(x, Wq, Wk, xsum, rs);
  rankk<<<512, 256, 0, stream>>>(rs, flag);
  attn_mfma<<<640, 256, 0, stream>>>(qbf, kbf, vtbf, flag, pl, pacc);
  attn_combine<<<dim3(BB, 64), 256, 0, stream>>>(pl, pacc, flag, out);
}

// Round 18
// 118.511 us; speedup vs baseline: 1.0621x; 1.0621x over previous
//
#include <hip/hip_runtime.h>
#include <math.h>

// Problem constants
#define BB 4
#define TT 4096
#define CC 1024
#define HS 64
#define KSEL 2048
#define NSPL 16   // KV splits per row-block
#define SWLOG 8   // split width = 256
#define SW 256

typedef float f32x4 __attribute__((ext_vector_type(4)));
typedef short short8 __attribute__((ext_vector_type(8)));

__device__ __forceinline__ unsigned short f2bf(float f) {
  union { float f; unsigned int u; } c;
  c.f = f;
  const unsigned int u = c.u;
  return (unsigned short)((u + 0x7FFFu + ((u >> 16) & 1u)) >> 16);  // RTNE
}

// packed f32x2 -> bf16x2 (RTNE), single HW instruction
__device__ __forceinline__ unsigned cvtpk(float lo, float hi) {
  unsigned r;
  asm("v_cvt_pk_bf16_f32 %0, %1, %2" : "=v"(r) : "v"(lo), "v"(hi));
  return r;
}

// ---------------------------------------------------------------------------
// conv_w: Wq|Wk|Wv fp32 -> bf16 B-fragment layout; also zeroes xsum (the
// only accumulator) -- kernel-boundary ordering makes this safe, no fence.
// ---------------------------------------------------------------------------
__global__ __launch_bounds__(256) void conv_w(const float* __restrict__ Wq,
                                              const float* __restrict__ Wk,
                                              const float* __restrict__ Wv,
                                              unsigned short* __restrict__ wbf,
                                              float* __restrict__ xsum) {
  const int gid = blockIdx.x * 256 + threadIdx.x;  // 0..24575
  if (gid < 1024) ((float4*)xsum)[gid] = make_float4(0.f, 0.f, 0.f, 0.f);
  const int kt = gid / 768;
  const int rem = gid - kt * 768;
  const int nt = rem >> 6, lane = rem & 63;
  const int col = nt * 16 + (lane & 15);
  const float* W = (col < 64) ? Wq : ((col < 128) ? Wk : Wv);
  const int cl = col & 63;
  const int k0 = kt * 32 + (lane >> 4) * 8;
  unsigned short tmp[8];
#pragma unroll
  for (int i = 0; i < 8; i++) tmp[i] = f2bf(W[(size_t)(k0 + i) * HS + cl]);
  uint4 o;
  o.x = tmp[0] | ((unsigned)tmp[1] << 16);
  o.y = tmp[2] | ((unsigned)tmp[3] << 16);
  o.z = tmp[4] | ((unsigned)tmp[5] << 16);
  o.w = tmp[6] | ((unsigned)tmp[7] << 16);
  *(uint4*)(wbf + (size_t)gid * 8) = o;
}

// ---------------------------------------------------------------------------
// fusedproj (R6/R13-proven): reads x ONCE. 512 blocks x 32 rows. Per 256-col
// chunk: stage bf16 into XOR-swizzled LDS, atomicAdd fp32 column sums into
// xsum, MFMA against wbf (L2-hot). Writes q (prescaled 2^-5), k row-major
// bf16, V transposed vt[b][d][t].
// ---------------------------------------------------------------------------
#define PR 32
__global__ __launch_bounds__(256) void fusedproj(
    const float* __restrict__ x, const unsigned short* __restrict__ wbf,
    float* __restrict__ xsum, unsigned short* __restrict__ qbf,
    unsigned short* __restrict__ kbf, unsigned short* __restrict__ vtbf) {
  __shared__ unsigned short Xs[PR][256];  // 16 KB, granule-XOR-swizzled
  __shared__ float xsred[4][256];
  const int rb = blockIdx.x;  // 512 blocks
  const size_t r0 = (size_t)rb * PR;
  const int tid = threadIdx.x;
  const int wid = tid >> 6, lane = tid & 63;
  const int lhi = lane >> 4, llo = lane & 15;
  const int mt = wid >> 1, nh = wid & 1;
  const int cl = tid & 63, rg = tid >> 6;
  const int bidx = rb >> 7;

  f32x4 acc[6];
#pragma unroll
  for (int n = 0; n < 6; n++) acc[n] = (f32x4){0.f, 0.f, 0.f, 0.f};

  float4 pf[8];
#pragma unroll
  for (int rr = 0; rr < 8; rr++)
    pf[rr] = *(const float4*)(x + (r0 + rg * 8 + rr) * CC + cl * 4);

  for (int ch = 0; ch < 4; ch++) {
    float ps0 = 0.f, ps1 = 0.f, ps2 = 0.f, ps3 = 0.f;
#pragma unroll
    for (int rr = 0; rr < 8; rr++) {
      const int row = rg * 8 + rr;
      float4 v = pf[rr];
      ps0 += v.x; ps1 += v.y; ps2 += v.z; ps3 += v.w;
      *(uint2*)((char*)&Xs[0][0] + row * 512 +
                ((((cl >> 1) ^ (row & 7))) << 4) + ((cl & 1) << 3)) =
          make_uint2(cvtpk(v.x, v.y), cvtpk(v.z, v.w));
    }
    xsred[rg][cl * 4 + 0] = ps0;
    xsred[rg][cl * 4 + 1] = ps1;
    xsred[rg][cl * 4 + 2] = ps2;
    xsred[rg][cl * 4 + 3] = ps3;
    __syncthreads();
    // issue next-chunk prefetch NOW; latency hides under atomic + MFMA
    if (ch < 3) {
#pragma unroll
      for (int rr = 0; rr < 8; rr++)
        pf[rr] = *(const float4*)(x + (r0 + rg * 8 + rr) * CC +
                                  (ch + 1) * 256 + cl * 4);
    }
    atomicAdd(&xsum[bidx * CC + ch * 256 + tid],
              xsred[0][tid] + xsred[1][tid] + xsred[2][tid] + xsred[3][tid]);
    const int row = mt * 16 + llo;
#pragma unroll
    for (int ktl = 0; ktl < 8; ktl++) {
      short8 af = *(const short8*)((const char*)&Xs[0][0] + row * 512 +
                                   ((((ktl << 2) + lhi) ^ (row & 7)) << 4));
      const unsigned short* bp =
          wbf + (((size_t)(ch * 8 + ktl) * 12 + nh * 6) * 64 + lane) * 8;
#pragma unroll
      for (int n = 0; n < 6; n++) {
        short8 bf = *(const short8*)(bp + n * 64 * 8);
        acc[n] = __builtin_amdgcn_mfma_f32_16x16x32_bf16(af, bf, acc[n], 0, 0, 0);
      }
    }
    __syncthreads();
  }
  const int rbg = (int)r0 + mt * 16 + lhi * 4;
#pragma unroll
  for (int n = 0; n < 6; n++) {
    const int col = (nh * 6 + n) * 16 + llo;
    const int mat = col >> 6, cl2 = col & 63;
    if (mat == 0) {
#pragma unroll
      for (int r = 0; r < 4; r++)
        qbf[(size_t)(rbg + r) * HS + cl2] = f2bf(acc[n][r] * 0.03125f);
    } else if (mat == 1) {
#pragma unroll
      for (int r = 0; r < 4; r++)
        kbf[(size_t)(rbg + r) * HS + cl2] = f2bf(acc[n][r]);
    } else {
      const int bb = rbg >> 12, tloc = rbg & (TT - 1);
      *(uint2*)(vtbf + ((size_t)bb * HS + cl2) * TT + tloc) =
          make_uint2(cvtpk(acc[n][0], acc[n][1]), cvtpk(acc[n][2], acc[n][3]));
    }
  }
}

// ---------------------------------------------------------------------------
// rowsums_x (R15-proven conflict-free): 256 blocks x 512 thr. Lane qu reads
// elements (qu + e*8)*4 -- all 32 banks hit exactly once per wave access.
// Prologue computes w = Wq (Wk^T xsum); main: rs[row] = x[row] . w.
// ---------------------------------------------------------------------------
__global__ __launch_bounds__(512) void rowsums_x(
    const float* __restrict__ x, const float* __restrict__ Wq,
    const float* __restrict__ Wk, const float* __restrict__ xsum,
    float* __restrict__ rs) {
  __shared__ float xsl[CC];
  __shared__ float kred[8][HS];
  __shared__ float ksl[HS];
  __shared__ float wl[CC];
  const int g = blockIdx.x;  // 256 blocks
  const int tid = threadIdx.x;
  const int b = g >> 6;
  *(float2*)(xsl + tid * 2) = *(const float2*)(xsum + b * CC + tid * 2);
  __syncthreads();
  {
    const int g8 = tid >> 6, d = tid & 63;
    const float* wkp = Wk + (size_t)(g8 * 128) * HS + d;
    float s = 0.f;
    for (int c = 0; c < 128; c++) s += xsl[g8 * 128 + c] * wkp[(size_t)c * HS];
    kred[g8][d] = s;
  }
  __syncthreads();
  if (tid < 64) {
    float s = 0.f;
#pragma unroll
    for (int g8 = 0; g8 < 8; g8++) s += kred[g8][tid];
    ksl[tid] = s;
  }
  __syncthreads();
#pragma unroll
  for (int p = 0; p < 2; p++) {
    const int c = tid * 2 + p;
    const float* wqp = Wq + (size_t)c * HS;
    float s = 0.f;
#pragma unroll
    for (int d4 = 0; d4 < 16; d4++) {
      float4 a = *(const float4*)(wqp + d4 * 4);
      float4 kk = *(const float4*)(ksl + d4 * 4);
      s += a.x * kk.x + a.y * kk.y + a.z * kk.z + a.w * kk.w;
    }
    wl[c] = s;
  }
  __syncthreads();
  const size_t row = (size_t)g * 64 + (tid >> 3);
  const int qu = tid & 7;
  const float* xr = x + row * CC;
  float s = 0.f;
#pragma unroll
  for (int e = 0; e < 32; e++) {
    const int off = (qu + e * 8) * 4;
    float4 v = *(const float4*)(xr + off);
    float4 w4 = *(const float4*)(wl + off);
    s += v.x * w4.x + v.y * w4.y + v.z * w4.z + v.w * w4.w;
  }
  s += __shfl_xor(s, 1);
  s += __shfl_xor(s, 2);
  s += __shfl_xor(s, 4);
  if (qu == 0) rs[row] = s;
}

// ---------------------------------------------------------------------------
// rankk (R6-proven): flag[t] = t in top-2048 (ties: lower index). 512 blocks.
// ---------------------------------------------------------------------------
__global__ __launch_bounds__(256) void rankk(const float* __restrict__ rs,
                                             int* __restrict__ flag) {
  __shared__ float rl[TT];
  const int g = blockIdx.x;  // B*128
  const int b = g >> 7, chunk = g & 127;
  const int tid = threadIdx.x;
  const float* rsb = rs + (size_t)b * TT;
  for (int e = tid; e < TT / 4; e += 256)
    *(float4*)(rl + e * 4) = *(const float4*)(rsb + e * 4);
  __syncthreads();
  const int cand = tid >> 3, qu = tid & 7;
  const int t = chunk * 32 + cand;
  const float my = rl[t];
  int cnt = 0;
  for (int e = 0; e < 128; e++) {
    const int s = qu * 512 + e * 4;
    float4 v = *(const float4*)(rl + s);
    cnt += (v.x > my) || (v.x == my && (s + 0) < t);
    cnt += (v.y > my) || (v.y == my && (s + 1) < t);
    cnt += (v.z > my) || (v.z == my && (s + 2) < t);
    cnt += (v.w > my) || (v.w == my && (s + 3) < t);
  }
  cnt += __shfl_xor(cnt, 1);
  cnt += __shfl_xor(cnt, 2);
  cnt += __shfl_xor(cnt, 4);
  if (qu == 0) flag[(size_t)b * TT + t] = (cnt < KSEL) ? 1 : 0;
}

// ---------------------------------------------------------------------------
// compact (R8-proven wave-scan) + worklist build: flags -> ascending idx;
// tail emits the dense list of active (b,rb,split) units + per-batch count.
// Consumed by attn via kernel-boundary ordering (NO device fences).
// ---------------------------------------------------------------------------
__global__ __launch_bounds__(256) void compact(const int* __restrict__ flag,
                                               int* __restrict__ idx,
                                               int* __restrict__ wlist,
                                               int* __restrict__ wcnt) {
  __shared__ int wsum[4];
  __shared__ int woff[4];
  const int b = blockIdx.x;
  const int tid = threadIdx.x;
  const int wid = tid >> 6, lane = tid & 63;
  const int* fb = flag + (size_t)b * TT;
  const int base = tid * 16;
  int f[16];
  int cnt = 0;
#pragma unroll
  for (int e4 = 0; e4 < 4; e4++) {
    int4 v = *(const int4*)(fb + base + e4 * 4);
    f[e4 * 4 + 0] = v.x; f[e4 * 4 + 1] = v.y;
    f[e4 * 4 + 2] = v.z; f[e4 * 4 + 3] = v.w;
    cnt += v.x + v.y + v.z + v.w;
  }
  int sc = cnt;
#pragma unroll
  for (int d = 1; d < 64; d <<= 1) {
    int v = __shfl_up(sc, d);
    if (lane >= d) sc += v;
  }
  if (lane == 63) wsum[wid] = sc;
  __syncthreads();
  if (tid == 0) {
    int a = 0;
#pragma unroll
    for (int w = 0; w < 4; w++) { woff[w] = a; a += wsum[w]; }
  }
  __syncthreads();
  int pos = woff[wid] + sc - cnt;
#pragma unroll
  for (int e = 0; e < 16; e++)
    if (f[e]) idx[(size_t)b * KSEL + (pos++)] = base + e;

  // ---- worklist build: active splits per row-block (tid<64 = wave 0) ----
  __syncthreads();  // idx writes visible within block
  if (tid < 64) {
    const int nact = (idx[(size_t)b * KSEL + tid * 32 + 31] >> SWLOG) + 1;
    int scan = nact;
#pragma unroll
    for (int d = 1; d < 64; d <<= 1) {
      int v = __shfl_up(scan, d);
      if (tid >= d) scan += v;
    }
    if (tid == 63) wcnt[b] = scan;
    int excl = scan - nact;
    for (int s2 = 0; s2 < nact; s2++)
      wlist[b * 1024 + excl + s2] = (b << 10) | (tid << 4) | s2;
  }
}

// ---------------------------------------------------------------------------
// attn_mfma: worklist-packed. 640 blocks x 4 waves; each wave grid-strides
// the dense unit list (every resident wave ACTIVE). Inner compute identical
// to R6/R13: swapped QK^T + no-max softmax, ping-pong K/V prefetch,
// streaming pl/pacc writes.
// ---------------------------------------------------------------------------
struct KF { short8 a0, a1, b0, b1; };
struct VF { short8 v0, v1, v2, v3; };

__global__ __launch_bounds__(256) void attn_mfma(
    const unsigned short* __restrict__ qbf,
    const unsigned short* __restrict__ kbf,
    const unsigned short* __restrict__ vtbf, const int* __restrict__ idx,
    const int* __restrict__ wlist, const int* __restrict__ wcnt,
    float* __restrict__ pl, float* __restrict__ pacc) {
  __shared__ unsigned short P_lds[4][32][40];
  const int tid = threadIdx.x;
  const int wid = tid >> 6, lane = tid & 63;
  const int lhi = lane >> 4, llo = lane & 15;
  const int c0 = wcnt[0], c1 = wcnt[1], c2 = wcnt[2], c3 = wcnt[3];
  const int total = c0 + c1 + c2 + c3;

  for (int u = blockIdx.x * 4 + wid; u < total; u += gridDim.x * 4) {
    int rem = u, b;
    if (rem >= c0) {
      rem -= c0;
      if (rem >= c1) {
        rem -= c1;
        if (rem >= c2) { rem -= c2; b = 3; } else b = 2;
      } else b = 1;
    } else b = 0;
    const int e = wlist[b * 1024 + rem];
    const int rb = (e >> 4) & 63;
    const int s = e & 15;
    const size_t rbase = (size_t)b * KSEL + rb * 32;
    const int tmaxblk = idx[rbase + 31];
    const int jlo = s << SWLOG;

    const int trow0 = idx[rbase + llo];
    const int trow1 = idx[rbase + 16 + llo];
    short8 qf[2][2];
    {
      const unsigned short* qp0 = qbf + ((size_t)b * TT + trow0) * HS + lhi * 8;
      const unsigned short* qp1 = qbf + ((size_t)b * TT + trow1) * HS + lhi * 8;
      qf[0][0] = *(const short8*)(qp0);
      qf[0][1] = *(const short8*)(qp0 + 32);
      qf[1][0] = *(const short8*)(qp1);
      qf[1][1] = *(const short8*)(qp1 + 32);
    }
    f32x4 o[2][4];
#pragma unroll
    for (int mtt = 0; mtt < 2; mtt++)
#pragma unroll
      for (int n = 0; n < 4; n++) o[mtt][n] = (f32x4){0.f, 0.f, 0.f, 0.f};
    float lsum[2] = {0.f, 0.f};

    const unsigned short* kb = kbf + (size_t)b * TT * HS;
    const unsigned short* vb = vtbf + (size_t)b * HS * TT;
    const int jend = min(tmaxblk + 1, jlo + SW);

    auto loadK = [&](int j0) {
      KF K;
      const unsigned short* kp = kb + (size_t)(j0 + llo) * HS + lhi * 8;
      K.a0 = *(const short8*)(kp);
      K.a1 = *(const short8*)(kp + 32);
      K.b0 = *(const short8*)(kp + 16 * HS);
      K.b1 = *(const short8*)(kp + 16 * HS + 32);
      return K;
    };
    auto loadV = [&](int j0) {
      VF V;
      const unsigned short* vp = vb + (size_t)llo * TT + j0 + lhi * 8;
      V.v0 = *(const short8*)(vp);
      V.v1 = *(const short8*)(vp + 16 * TT);
      V.v2 = *(const short8*)(vp + 32 * TT);
      V.v3 = *(const short8*)(vp + 48 * TT);
      return V;
    };

    auto body = [&](int j0, const KF& K, const VF& V) {
      f32x4 sc[2][2];
#pragma unroll
      for (int mtt = 0; mtt < 2; mtt++) {
        f32x4 a = (f32x4){0.f, 0.f, 0.f, 0.f};
        a = __builtin_amdgcn_mfma_f32_16x16x32_bf16(K.a0, qf[mtt][0], a, 0, 0, 0);
        a = __builtin_amdgcn_mfma_f32_16x16x32_bf16(K.a1, qf[mtt][1], a, 0, 0, 0);
        sc[mtt][0] = a;
        f32x4 c = (f32x4){0.f, 0.f, 0.f, 0.f};
        c = __builtin_amdgcn_mfma_f32_16x16x32_bf16(K.b0, qf[mtt][0], c, 0, 0, 0);
        c = __builtin_amdgcn_mfma_f32_16x16x32_bf16(K.b1, qf[mtt][1], c, 0, 0, 0);
        sc[mtt][1] = c;
      }
#pragma unroll
      for (int mtt = 0; mtt < 2; mtt++) {
        const int tr = (mtt == 0) ? trow0 : trow1;
        float p[8];
#pragma unroll
        for (int kt = 0; kt < 2; kt++)
#pragma unroll
          for (int r = 0; r < 4; r++) {
            const int kk = j0 + kt * 16 + lhi * 4 + r;
            const float ex = __expf(sc[mtt][kt][r]);
            p[kt * 4 + r] = (kk <= tr) ? ex : 0.f;
          }
        lsum[mtt] += ((p[0] + p[1]) + (p[2] + p[3])) +
                     ((p[4] + p[5]) + (p[6] + p[7]));
        *(uint2*)&P_lds[wid][mtt * 16 + llo][lhi * 4] =
            make_uint2(cvtpk(p[0], p[1]), cvtpk(p[2], p[3]));
        *(uint2*)&P_lds[wid][mtt * 16 + llo][16 + lhi * 4] =
            make_uint2(cvtpk(p[4], p[5]), cvtpk(p[6], p[7]));
      }
      // PV (same-wave DS ordering -> no barrier needed)
      short8 pa0 = *(const short8*)&P_lds[wid][llo][lhi * 8];
      short8 pa1 = *(const short8*)&P_lds[wid][16 + llo][lhi * 8];
      o[0][0] = __builtin_amdgcn_mfma_f32_16x16x32_bf16(pa0, V.v0, o[0][0], 0, 0, 0);
      o[1][0] = __builtin_amdgcn_mfma_f32_16x16x32_bf16(pa1, V.v0, o[1][0], 0, 0, 0);
      o[0][1] = __builtin_amdgcn_mfma_f32_16x16x32_bf16(pa0, V.v1, o[0][1], 0, 0, 0);
      o[1][1] = __builtin_amdgcn_mfma_f32_16x16x32_bf16(pa1, V.v1, o[1][1], 0, 0, 0);
      o[0][2] = __builtin_amdgcn_mfma_f32_16x16x32_bf16(pa0, V.v2, o[0][2], 0, 0, 0);
      o[1][2] = __builtin_amdgcn_mfma_f32_16x16x32_bf16(pa1, V.v2, o[1][2], 0, 0, 0);
      o[0][3] = __builtin_amdgcn_mfma_f32_16x16x32_bf16(pa0, V.v3, o[0][3], 0, 0, 0);
      o[1][3] = __builtin_amdgcn_mfma_f32_16x16x32_bf16(pa1, V.v3, o[1][3], 0, 0, 0);
    };

    int j0 = jlo;
    KF ka = loadK(j0), kb2;
    VF va = loadV(j0), vb2;
    for (;;) {
      if (j0 + 32 < jend) { kb2 = loadK(j0 + 32); vb2 = loadV(j0 + 32); }
      body(j0, ka, va);
      j0 += 32;
      if (j0 >= jend) break;
      if (j0 + 32 < jend) { ka = loadK(j0 + 32); va = loadV(j0 + 32); }
      body(j0, kb2, vb2);
      j0 += 32;
      if (j0 >= jend) break;
    }

    // epilogue: streaming partial writes (combine is a plain sum)
    lsum[0] += __shfl_xor(lsum[0], 16);
    lsum[0] += __shfl_xor(lsum[0], 32);
    lsum[1] += __shfl_xor(lsum[1], 16);
    lsum[1] += __shfl_xor(lsum[1], 32);
    if (lane < 16) {
      pl[(rbase + llo) * NSPL + s] = lsum[0];
      pl[(rbase + 16 + llo) * NSPL + s] = lsum[1];
    }
#pragma unroll
    for (int mtt = 0; mtt < 2; mtt++)
#pragma unroll
      for (int r = 0; r < 4; r++) {
        const size_t rowi = rbase + mtt * 16 + lhi * 4 + r;
#pragma unroll
        for (int n = 0; n < 4; n++)
          pacc[(rowi * NSPL + s) * HS + n * 16 + llo] = o[mtt][n][r];
      }
  }
}

// ---------------------------------------------------------------------------
// attn_combine (R6-proven): plain sums over active splits, then normalize.
// ---------------------------------------------------------------------------
__global__ __launch_bounds__(256) void attn_combine(
    const float* __restrict__ pl, const float* __restrict__ pacc,
    const int* __restrict__ idx, float* __restrict__ out) {
  const int b = blockIdx.x;
  const int i0 = blockIdx.y * 32;
  const int tid = threadIdx.x;
  const int r = tid >> 3, dg = tid & 7;
  const size_t rowi = (size_t)b * KSEL + i0 + r;
  const int t_r = idx[rowi];
  const int ns = (t_r >> SWLOG) + 1;
  float L = 0.f;
  float o[8] = {0.f, 0.f, 0.f, 0.f, 0.f, 0.f, 0.f, 0.f};
  for (int s = 0; s < ns; s++) {
    L += pl[rowi * NSPL + s];
    const float* pa = pacc + (rowi * NSPL + s) * HS + dg * 8;
    float4 a0 = *(const float4*)(pa);
    float4 a1 = *(const float4*)(pa + 4);
    o[0] += a0.x; o[1] += a0.y; o[2] += a0.z; o[3] += a0.w;
    o[4] += a1.x; o[5] += a1.y; o[6] += a1.z; o[7] += a1.w;
  }
  const float invl = 1.0f / L;
  float* op = out + rowi * HS + dg * 8;
  *(float4*)(op) = make_float4(o[0] * invl, o[1] * invl, o[2] * invl, o[3] * invl);
  *(float4*)(op + 4) = make_float4(o[4] * invl, o[5] * invl, o[6] * invl, o[7] * invl);
}

// ---------------------------------------------------------------------------
extern "C" void kernel_launch(void* const* d_in, const int* in_sizes, int n_in,
                              void* d_out, int out_size, void* d_ws,
                              size_t ws_size, hipStream_t stream) {
  const float* x = (const float*)d_in[0];
  const float* Wq = (const float*)d_in[1];
  const float* Wk = (const float*)d_in[2];
  const float* Wv = (const float*)d_in[3];
  float* out = (float*)d_out;

  float* wsf = (float*)d_ws;
  // Region 0..33.55MB: pacc (attn phase) overlaps selection-phase scratch
  // (xsum, rs, flag, wbf), all dead before attn_mfma runs.
  float* pacc = wsf;                         // 8,388,608 f (BB*KSEL*NSPL*HS)
  float* xsum = wsf;                         // 4,096 f (atomic accum)
  float* rs = xsum + 4096;                   // 16,384 f
  int* flag = (int*)(rs + 16384);            // 16,384 i
  unsigned short* wbf = (unsigned short*)(flag + 16384);  // 196,608 us
  // Past pacc: buffers live through attn.
  unsigned short* qbf = (unsigned short*)(pacc + 8388608);  // 1,048,576 us
  unsigned short* kbf = qbf + 1048576;       // 1,048,576 us
  unsigned short* vtbf = kbf + 1048576;      // 1,048,576 us
  int* idxp = (int*)(vtbf + 1048576);        // 8,192 i
  float* pl = (float*)(idxp + 8192);         // 131,072 f
  int* wcnt = (int*)(pl + 131072);           // 4 i
  int* wlist = wcnt + 4;                     // 4,096 i

  conv_w<<<96, 256, 0, stream>>>(Wq, Wk, Wv, wbf, xsum);
  fusedproj<<<512, 256, 0, stream>>>(x, wbf, xsum, qbf, kbf, vtbf);
  rowsums_x<<<256, 512, 0, stream>>>(x, Wq, Wk, xsum, rs);
  rankk<<<512, 256, 0, stream>>>(rs, flag);
  compact<<<BB, 256, 0, stream>>>(flag, idxp, wlist, wcnt);
  attn_mfma<<<640, 256, 0, stream>>>(qbf, kbf, vtbf, idxp, wlist, wcnt, pl, pacc);
  attn_combine<<<dim3(BB, 64), 256, 0, stream>>>(pl, pacc, idxp, out);
}